// Round 2
// baseline (834.196 us; speedup 1.0000x reference)
//
#include <hip/hip_runtime.h>
#include <cstdint>

#define NN 100000
#define NE 1600000
#define INDIM 165
#define HID 64

constexpr int SCAN_TPB = 256;
constexpr int SCAN_ITEMS = 8;
constexpr int SCAN_BLK = SCAN_TPB * SCAN_ITEMS; // 2048

// ---------------- CSR build ----------------

__global__ void k_deg(const int* __restrict__ dst, int* __restrict__ deg, int ne) {
    int e = blockIdx.x * blockDim.x + threadIdx.x;
    if (e < ne) atomicAdd(&deg[dst[e]], 1);
}

__global__ void k_scan1(const int* __restrict__ in, int* __restrict__ out,
                        int* __restrict__ bsum, int n) {
    __shared__ int wsum[SCAN_TPB / 64];
    const int tid = threadIdx.x;
    const int lane = tid & 63, wid = tid >> 6;
    const int base = blockIdx.x * SCAN_BLK + tid * SCAN_ITEMS;
    int v[SCAN_ITEMS];
    int tsum = 0;
#pragma unroll
    for (int i = 0; i < SCAN_ITEMS; ++i) {
        int idx = base + i;
        v[i] = (idx < n) ? in[idx] : 0;
        tsum += v[i];
    }
    int x = tsum;
#pragma unroll
    for (int off = 1; off < 64; off <<= 1) {
        int y = __shfl_up(x, off, 64);
        if (lane >= off) x += y;
    }
    if (lane == 63) wsum[wid] = x;
    __syncthreads();
    int woff = 0;
#pragma unroll
    for (int w = 0; w < SCAN_TPB / 64; ++w)
        if (w < wid) woff += wsum[w];
    int run = woff + x - tsum;
#pragma unroll
    for (int i = 0; i < SCAN_ITEMS; ++i) {
        int idx = base + i;
        if (idx < n) out[idx] = run;
        run += v[i];
    }
    if (tid == SCAN_TPB - 1) bsum[blockIdx.x] = woff + x;
}

__global__ void k_scan2(int* bsum, int nb) {
    const int lane = threadIdx.x; // blockDim = 64, nb <= 64
    int v = (lane < nb) ? bsum[lane] : 0;
    int x = v;
#pragma unroll
    for (int off = 1; off < 64; off <<= 1) {
        int y = __shfl_up(x, off, 64);
        if (lane >= off) x += y;
    }
    if (lane < nb) bsum[lane] = x - v;
    if (lane == nb - 1) bsum[nb] = x;
}

// adds block offsets; writes BOTH rowptr and cursor (fuses old k_copy)
__global__ void k_scan3(int* __restrict__ out, int* __restrict__ cursor,
                        const int* __restrict__ bsum, int n, int nb) {
    const int off = bsum[blockIdx.x];
#pragma unroll
    for (int i = 0; i < SCAN_ITEMS; ++i) {
        int id = blockIdx.x * SCAN_BLK + i * SCAN_TPB + threadIdx.x;
        if (id < n) {
            int v = out[id] + off;
            out[id] = v;
            cursor[id] = v;
        }
    }
    if (blockIdx.x == 0 && threadIdx.x == 0) out[n] = bsum[nb];
}

__global__ void k_fill(const int* __restrict__ src, const int* __restrict__ dst,
                       int* __restrict__ cursor, int* __restrict__ col, int ne) {
    int e = blockIdx.x * blockDim.x + threadIdx.x;
    if (e < ne) {
        int p = atomicAdd(&cursor[dst[e]], 1);
        col[p] = src[e];
    }
}

// ---------------- fused dual linear: Y = X@Wl, R = X@Wr ----------------
// 256 threads = 4 waves per block; block owns 64 nodes. All waves share one
// 64x64 x-tile in LDS (XOR-swizzled, conflict-free, 16 KB). Wave w computes a
// 32-column slice of the concatenated [Wl|Wr] 128-col output -> 32 fp32
// accumulators/thread (~48 VGPR), weight rows are wave-uniform scalar loads.
// 1563 blocks x 4 waves = 6252 waves -> ~76% occupancy (vs 19% before).

template <int K>
__global__ __launch_bounds__(256) void k_linear(const float* __restrict__ X,
                                                const float* __restrict__ Wl,
                                                const float* __restrict__ Wr,
                                                float* __restrict__ Y,
                                                float* __restrict__ R, int n) {
    __shared__ float xs[64 * 64];
    const int tid = threadIdx.x;
    const int lane = tid & 63;   // node within tile
    const int wave = tid >> 6;   // 0..3
    const int nodeBase = blockIdx.x * 64;
    const float* __restrict__ W = (wave < 2) ? Wl : Wr;
    const int colBase = (wave & 1) * 32;

    float acc[32];
#pragma unroll
    for (int t = 0; t < 32; ++t) acc[t] = 0.f;

    for (int c = 0; c < K; c += 64) {
        const int kw = (K - c < 64) ? (K - c) : 64;
        __syncthreads();
        // stage 64 nodes x kw feats, transposed + XOR-swizzled
        for (int idx = tid; idx < 64 * 64; idx += 256) {
            const int f = idx & 63;       // consecutive lanes -> contiguous feats
            const int node = idx >> 6;
            if (f < kw) {
                int gn = nodeBase + node;
                if (gn >= n) gn = n - 1;
                xs[f * 64 + (node ^ f)] = X[(size_t)gn * K + c + f];
            }
        }
        __syncthreads();
        for (int kk = 0; kk < kw; ++kk) {
            const float xv = xs[kk * 64 + (lane ^ kk)]; // = X[node=lane][c+kk]
            const float* __restrict__ w = W + (size_t)(c + kk) * HID + colBase;
#pragma unroll
            for (int t = 0; t < 32; ++t) acc[t] = fmaf(xv, w[t], acc[t]);
        }
    }

    // epilogue: two LDS-transpose passes (16 KB holds one 64x64 half)
    __syncthreads();
    if (wave < 2) {
#pragma unroll
        for (int t = 0; t < 32; ++t) {
            const int col = colBase + t;
            xs[col * 64 + (lane ^ col)] = acc[t]; // lane = node
        }
    }
    __syncthreads();
    for (int r = 0; r < 16; ++r) {
        const int node = r * 4 + wave;
        const int gn = nodeBase + node;
        if (gn < n) Y[(size_t)gn * HID + lane] = xs[lane * 64 + (node ^ lane)];
    }
    __syncthreads();
    if (wave >= 2) {
#pragma unroll
        for (int t = 0; t < 32; ++t) {
            const int col = colBase + t;
            xs[col * 64 + (lane ^ col)] = acc[t];
        }
    }
    __syncthreads();
    for (int r = 0; r < 16; ++r) {
        const int node = r * 4 + wave;
        const int gn = nodeBase + node;
        if (gn < n) R[(size_t)gn * HID + lane] = xs[lane * 64 + (node ^ lane)];
    }
}

// ---------------- aggregation (+ optional fused classifier) ----------------

template <bool CLS>
__global__ __launch_bounds__(256) void k_agg(const float* __restrict__ Y,
                                             const float* __restrict__ Rm,
                                             const float* __restrict__ bias,
                                             const int* __restrict__ rowptr,
                                             const int* __restrict__ col,
                                             float* __restrict__ H,
                                             const float* __restrict__ Wc,
                                             const float* __restrict__ bc,
                                             float* __restrict__ out, int n) {
    const int lane = threadIdx.x & 63;
    const int node = blockIdx.x * 4 + (threadIdx.x >> 6);
    if (node >= n) return;
    const int s = rowptr[node], e = rowptr[node + 1];
    float a0 = 0.f, a1 = 0.f, a2 = 0.f, a3 = 0.f;
    int i = s;
    for (; i + 3 < e; i += 4) {
        int s0 = col[i], s1 = col[i + 1], s2 = col[i + 2], s3 = col[i + 3];
        a0 += Y[(size_t)s0 * HID + lane];
        a1 += Y[(size_t)s1 * HID + lane];
        a2 += Y[(size_t)s2 * HID + lane];
        a3 += Y[(size_t)s3 * HID + lane];
    }
    for (; i < e; ++i) a0 += Y[(size_t)col[i] * HID + lane];
    float acc = (a0 + a1) + (a2 + a3);
    const int deg = e - s;
    float h = acc / (float)(deg > 1 ? deg : 1) + bias[lane] + Rm[(size_t)node * HID + lane];
    h = fmaxf(h, 0.f);
    if (!CLS) {
        H[(size_t)node * HID + lane] = h;
    } else {
        float p0 = h * Wc[lane * 2 + 0];
        float p1 = h * Wc[lane * 2 + 1];
#pragma unroll
        for (int off = 32; off > 0; off >>= 1) {
            p0 += __shfl_xor(p0, off, 64);
            p1 += __shfl_xor(p1, off, 64);
        }
        if (lane == 0) {
            out[(size_t)node * 2 + 0] = p0 + bc[0];
            out[(size_t)node * 2 + 1] = p1 + bc[1];
        }
    }
}

// ---------------- launch ----------------

extern "C" void kernel_launch(void* const* d_in, const int* in_sizes, int n_in,
                              void* d_out, int out_size, void* d_ws, size_t ws_size,
                              hipStream_t stream) {
    const float* x   = (const float*)d_in[0];
    const int*   ei  = (const int*)d_in[1];
    const float* W1l = (const float*)d_in[2];
    const float* b1  = (const float*)d_in[3];
    const float* W1r = (const float*)d_in[4];
    const float* W2l = (const float*)d_in[5];
    const float* b2  = (const float*)d_in[6];
    const float* W2r = (const float*)d_in[7];
    const float* Wc  = (const float*)d_in[8];
    const float* bc  = (const float*)d_in[9];
    float* out = (float*)d_out;
    const int* src = ei;
    const int* dst = ei + NE;

    char* base = (char*)d_ws;
    size_t off = 0;
    auto alloc = [&](size_t bytes) {
        void* p = base + off;
        off = (off + bytes + 255) & ~(size_t)255;
        return p;
    };
    int*   deg    = (int*)alloc((size_t)NN * 4);
    int*   rowptr = (int*)alloc((size_t)(NN + 1) * 4);
    int*   cursor = (int*)alloc((size_t)NN * 4);
    int*   bsum   = (int*)alloc(256 * 4);
    int*   col    = (int*)alloc((size_t)NE * 4);
    float* Y      = (float*)alloc((size_t)NN * HID * 4);
    float* R      = (float*)alloc((size_t)NN * HID * 4);
    float* H1     = (float*)alloc((size_t)NN * HID * 4);

    const int nb = (NN + SCAN_BLK - 1) / SCAN_BLK; // 49
    const int eb = (NE + 255) / 256;               // 6250: 1 edge/thread

    hipMemsetAsync(deg, 0, (size_t)NN * 4, stream);
    k_deg<<<eb, 256, 0, stream>>>(dst, deg, NE);
    k_scan1<<<nb, SCAN_TPB, 0, stream>>>(deg, rowptr, bsum, NN);
    k_scan2<<<1, 64, 0, stream>>>(bsum, nb);
    k_scan3<<<nb, SCAN_TPB, 0, stream>>>(rowptr, cursor, bsum, NN, nb);
    k_fill<<<eb, 256, 0, stream>>>(src, dst, cursor, col, NE);

    k_linear<INDIM><<<(NN + 63) / 64, 256, 0, stream>>>(x, W1l, W1r, Y, R, NN);
    k_agg<false><<<(NN + 3) / 4, 256, 0, stream>>>(Y, R, b1, rowptr, col, H1,
                                                   nullptr, nullptr, nullptr, NN);
    k_linear<HID><<<(NN + 63) / 64, 256, 0, stream>>>(H1, W2l, W2r, Y, R, NN);
    k_agg<true><<<(NN + 3) / 4, 256, 0, stream>>>(Y, R, b2, rowptr, col, nullptr,
                                                  Wc, bc, out, NN);
}

// Round 3
// 554.336 us; speedup vs baseline: 1.5049x; 1.5049x over previous
//
#include <hip/hip_runtime.h>
#include <cstdint>

#define NN 100000
#define NE 1600000
#define INDIM 165
#define HID 64

constexpr int SCAN_TPB = 256;
constexpr int SCAN_ITEMS = 8;
constexpr int SCAN_BLK = SCAN_TPB * SCAN_ITEMS; // 2048

// ---------------- CSR build ----------------

__global__ void k_deg(const int* __restrict__ dst, int* __restrict__ deg, int ne) {
    int e = blockIdx.x * blockDim.x + threadIdx.x;
    if (e < ne) atomicAdd(&deg[dst[e]], 1);
}

__global__ void k_scan1(const int* __restrict__ in, int* __restrict__ out,
                        int* __restrict__ bsum, int n) {
    __shared__ int wsum[SCAN_TPB / 64];
    const int tid = threadIdx.x;
    const int lane = tid & 63, wid = tid >> 6;
    const int base = blockIdx.x * SCAN_BLK + tid * SCAN_ITEMS;
    int v[SCAN_ITEMS];
    int tsum = 0;
#pragma unroll
    for (int i = 0; i < SCAN_ITEMS; ++i) {
        int idx = base + i;
        v[i] = (idx < n) ? in[idx] : 0;
        tsum += v[i];
    }
    int x = tsum;
#pragma unroll
    for (int off = 1; off < 64; off <<= 1) {
        int y = __shfl_up(x, off, 64);
        if (lane >= off) x += y;
    }
    if (lane == 63) wsum[wid] = x;
    __syncthreads();
    int woff = 0;
#pragma unroll
    for (int w = 0; w < SCAN_TPB / 64; ++w)
        if (w < wid) woff += wsum[w];
    int run = woff + x - tsum;
#pragma unroll
    for (int i = 0; i < SCAN_ITEMS; ++i) {
        int idx = base + i;
        if (idx < n) out[idx] = run;
        run += v[i];
    }
    if (tid == SCAN_TPB - 1) bsum[blockIdx.x] = woff + x;
}

__global__ void k_scan2(int* bsum, int nb) {
    const int lane = threadIdx.x; // blockDim = 64, nb <= 64
    int v = (lane < nb) ? bsum[lane] : 0;
    int x = v;
#pragma unroll
    for (int off = 1; off < 64; off <<= 1) {
        int y = __shfl_up(x, off, 64);
        if (lane >= off) x += y;
    }
    if (lane < nb) bsum[lane] = x - v;
    if (lane == nb - 1) bsum[nb] = x;
}

__global__ void k_scan3(int* __restrict__ out, int* __restrict__ cursor,
                        const int* __restrict__ bsum, int n, int nb) {
    const int off = bsum[blockIdx.x];
#pragma unroll
    for (int i = 0; i < SCAN_ITEMS; ++i) {
        int id = blockIdx.x * SCAN_BLK + i * SCAN_TPB + threadIdx.x;
        if (id < n) {
            int v = out[id] + off;
            out[id] = v;
            cursor[id] = v;
        }
    }
    if (blockIdx.x == 0 && threadIdx.x == 0) out[n] = bsum[nb];
}

__global__ void k_fill(const int* __restrict__ src, const int* __restrict__ dst,
                       int* __restrict__ cursor, int* __restrict__ col, int ne) {
    int e = blockIdx.x * blockDim.x + threadIdx.x;
    if (e < ne) {
        int p = atomicAdd(&cursor[dst[e]], 1);
        col[p] = src[e];
    }
}

// ---------------- fused dual linear: Y = X@Wl, R = X@Wr ----------------
// Register-tiled GEMM: [M=100000 x K] @ [K x 128] where cols 0..63 = Wl,
// 64..127 = Wr. Block = 256 threads, tile 128x128, K-chunk 32, LDS-staged
// X AND W (no wave-uniform/scalar-load gamble -> everything is ds_read).
// Thread micro-tile 8x8: per kk = 4 ds_read_b128 + 64 v_fma (VALU-bound).
// LDS 2*32*132*4 = 33 KB -> pad-4 keeps float4 reads 16B-aligned.

template <int K>
__global__ __launch_bounds__(256) void k_linear(const float* __restrict__ X,
                                                const float* __restrict__ Wl,
                                                const float* __restrict__ Wr,
                                                float* __restrict__ Y,
                                                float* __restrict__ R, int n) {
    constexpr int KC = 32;
    constexpr int MT = 128;
    constexpr int LDT = 132; // +4 pad: aligned float4, tolerable stage conflicts
    __shared__ float Xs[KC][LDT]; // Xs[k][m]
    __shared__ float Ws[KC][LDT]; // Ws[k][n]

    const int tid = threadIdx.x;
    const int m0 = (tid >> 4) * 8;  // node block (wave-broadcast reads)
    const int n0 = (tid & 15) * 8;  // col block
    const int nodeBase = blockIdx.x * MT;

    float acc[8][8];
#pragma unroll
    for (int i = 0; i < 8; ++i)
#pragma unroll
        for (int j = 0; j < 8; ++j) acc[i][j] = 0.f;

    for (int c = 0; c < K; c += KC) {
        const int kw = (K - c < KC) ? (K - c) : KC;
        __syncthreads();
        // stage X: element e -> k = e&31 (consec lanes = consec k: coalesced
        // 128B/half-wave global reads), m = e>>5. Zero-fill k >= kw.
#pragma unroll
        for (int i = 0; i < 16; ++i) {
            int e = tid + i * 256;
            int k = e & 31;
            int m = e >> 5;
            int gn = nodeBase + m;
            if (gn >= n) gn = n - 1;
            Xs[k][m] = (k < kw) ? X[(size_t)gn * K + c + k] : 0.f;
        }
        // stage W as float4: v -> k = v>>5, nf4 = v&31 (coalesced rows)
#pragma unroll
        for (int i = 0; i < 4; ++i) {
            int v = tid + i * 256;
            int k = v >> 5;
            int nf = (v & 31) * 4;
            float4 w;
            if (k < kw) {
                const float* sp = (nf < 64) ? (Wl + (size_t)(c + k) * HID + nf)
                                            : (Wr + (size_t)(c + k) * HID + (nf - 64));
                w = *(const float4*)sp;
            } else {
                w = make_float4(0.f, 0.f, 0.f, 0.f);
            }
            *(float4*)&Ws[k][nf] = w;
        }
        __syncthreads();
#pragma unroll 4
        for (int kk = 0; kk < KC; ++kk) {
            const float4 xa = *(const float4*)&Xs[kk][m0];
            const float4 xb = *(const float4*)&Xs[kk][m0 + 4];
            const float4 wa = *(const float4*)&Ws[kk][n0];
            const float4 wb = *(const float4*)&Ws[kk][n0 + 4];
            const float xm[8] = {xa.x, xa.y, xa.z, xa.w, xb.x, xb.y, xb.z, xb.w};
            const float wn[8] = {wa.x, wa.y, wa.z, wa.w, wb.x, wb.y, wb.z, wb.w};
#pragma unroll
            for (int i = 0; i < 8; ++i)
#pragma unroll
                for (int j = 0; j < 8; ++j)
                    acc[i][j] = fmaf(xm[i], wn[j], acc[i][j]);
        }
    }

    // epilogue: n0<64 -> Y, else -> R; coalesced float4 row stores
    float* __restrict__ dbuf = (n0 < HID) ? Y : R;
    const int nc = n0 & (HID - 1);
#pragma unroll
    for (int i = 0; i < 8; ++i) {
        const int gn = nodeBase + m0 + i;
        if (gn < n) {
            float4 lo = make_float4(acc[i][0], acc[i][1], acc[i][2], acc[i][3]);
            float4 hi = make_float4(acc[i][4], acc[i][5], acc[i][6], acc[i][7]);
            *(float4*)&dbuf[(size_t)gn * HID + nc] = lo;
            *(float4*)&dbuf[(size_t)gn * HID + nc + 4] = hi;
        }
    }
}

// ---------------- aggregation (+ optional fused classifier) ----------------

template <bool CLS>
__global__ __launch_bounds__(256) void k_agg(const float* __restrict__ Y,
                                             const float* __restrict__ Rm,
                                             const float* __restrict__ bias,
                                             const int* __restrict__ rowptr,
                                             const int* __restrict__ col,
                                             float* __restrict__ H,
                                             const float* __restrict__ Wc,
                                             const float* __restrict__ bc,
                                             float* __restrict__ out, int n) {
    const int lane = threadIdx.x & 63;
    const int node = blockIdx.x * 4 + (threadIdx.x >> 6);
    if (node >= n) return;
    const int s = rowptr[node], e = rowptr[node + 1];
    float a0 = 0.f, a1 = 0.f, a2 = 0.f, a3 = 0.f;
    int i = s;
    for (; i + 3 < e; i += 4) {
        int s0 = col[i], s1 = col[i + 1], s2 = col[i + 2], s3 = col[i + 3];
        a0 += Y[(size_t)s0 * HID + lane];
        a1 += Y[(size_t)s1 * HID + lane];
        a2 += Y[(size_t)s2 * HID + lane];
        a3 += Y[(size_t)s3 * HID + lane];
    }
    for (; i < e; ++i) a0 += Y[(size_t)col[i] * HID + lane];
    float acc = (a0 + a1) + (a2 + a3);
    const int deg = e - s;
    float h = acc / (float)(deg > 1 ? deg : 1) + bias[lane] + Rm[(size_t)node * HID + lane];
    h = fmaxf(h, 0.f);
    if (!CLS) {
        H[(size_t)node * HID + lane] = h;
    } else {
        float p0 = h * Wc[lane * 2 + 0];
        float p1 = h * Wc[lane * 2 + 1];
#pragma unroll
        for (int off = 32; off > 0; off >>= 1) {
            p0 += __shfl_xor(p0, off, 64);
            p1 += __shfl_xor(p1, off, 64);
        }
        if (lane == 0) {
            out[(size_t)node * 2 + 0] = p0 + bc[0];
            out[(size_t)node * 2 + 1] = p1 + bc[1];
        }
    }
}

// ---------------- launch ----------------

extern "C" void kernel_launch(void* const* d_in, const int* in_sizes, int n_in,
                              void* d_out, int out_size, void* d_ws, size_t ws_size,
                              hipStream_t stream) {
    const float* x   = (const float*)d_in[0];
    const int*   ei  = (const int*)d_in[1];
    const float* W1l = (const float*)d_in[2];
    const float* b1  = (const float*)d_in[3];
    const float* W1r = (const float*)d_in[4];
    const float* W2l = (const float*)d_in[5];
    const float* b2  = (const float*)d_in[6];
    const float* W2r = (const float*)d_in[7];
    const float* Wc  = (const float*)d_in[8];
    const float* bc  = (const float*)d_in[9];
    float* out = (float*)d_out;
    const int* src = ei;
    const int* dst = ei + NE;

    char* base = (char*)d_ws;
    size_t off = 0;
    auto alloc = [&](size_t bytes) {
        void* p = base + off;
        off = (off + bytes + 255) & ~(size_t)255;
        return p;
    };
    int*   deg    = (int*)alloc((size_t)NN * 4);
    int*   rowptr = (int*)alloc((size_t)(NN + 1) * 4);
    int*   cursor = (int*)alloc((size_t)NN * 4);
    int*   bsum   = (int*)alloc(256 * 4);
    int*   col    = (int*)alloc((size_t)NE * 4);
    float* Y      = (float*)alloc((size_t)NN * HID * 4);
    float* R      = (float*)alloc((size_t)NN * HID * 4);
    float* H1     = (float*)alloc((size_t)NN * HID * 4);

    const int nb = (NN + SCAN_BLK - 1) / SCAN_BLK; // 49
    const int eb = (NE + 255) / 256;               // 6250: 1 edge/thread

    hipMemsetAsync(deg, 0, (size_t)NN * 4, stream);
    k_deg<<<eb, 256, 0, stream>>>(dst, deg, NE);
    k_scan1<<<nb, SCAN_TPB, 0, stream>>>(deg, rowptr, bsum, NN);
    k_scan2<<<1, 64, 0, stream>>>(bsum, nb);
    k_scan3<<<nb, SCAN_TPB, 0, stream>>>(rowptr, cursor, bsum, NN, nb);
    k_fill<<<eb, 256, 0, stream>>>(src, dst, cursor, col, NE);

    k_linear<INDIM><<<(NN + 127) / 128, 256, 0, stream>>>(x, W1l, W1r, Y, R, NN);
    k_agg<false><<<(NN + 3) / 4, 256, 0, stream>>>(Y, R, b1, rowptr, col, H1,
                                                   nullptr, nullptr, nullptr, NN);
    k_linear<HID><<<(NN + 127) / 128, 256, 0, stream>>>(H1, W2l, W2r, Y, R, NN);
    k_agg<true><<<(NN + 3) / 4, 256, 0, stream>>>(Y, R, b2, rowptr, col, nullptr,
                                                  Wc, bc, out, NN);
}